// Round 3
// baseline (149.378 us; speedup 1.0000x reference)
//
#include <hip/hip_runtime.h>
#include <hip/hip_bf16.h>

// Problem constants (from reference): B=262144, D=256, S=16, C=10.
#define D_DIM 256
#define S_SYS 16
#define C_CLS 10
#define SPB   128   // samples per main-kernel block (bucket padding granule)
#define NB    4     // 8-sample batches per wave (32 samples/wave)

// Workspace layout (ints):
//   [0   .. 255]  hist    (16 bins, 64B-strided: hist[t*16])
//   [256 .. 511]  cursor  (scatter-mutated padded starts)
//   [512 .. 767]  pstart  (immutable padded starts, pstart[t*16])
//   [768]         ntot    (padded total sample count)
//   byte 4096+    idx     (sorted packed entries)
#define WS_HIST   0
#define WS_CURSOR 256
#define WS_PSTART 512
#define WS_NTOT   768
#define WS_IDX_BYTES 4096

// ---------------- init: zero hist + cursor (replaces hipMemsetAsync) --------
__global__ void init_k(int* __restrict__ ws) {
    int t = threadIdx.x;
    if (t < 512) ws[t] = 0;
}

// ---------------- histogram: count samples per system ----------------
__global__ __launch_bounds__(256) void hist_k(const int* __restrict__ sid, int n,
                                              int* __restrict__ hist) {
    __shared__ int lh[S_SYS];
    if (threadIdx.x < S_SYS) lh[threadIdx.x] = 0;
    __syncthreads();
    int i = blockIdx.x * 256 + threadIdx.x;
    if (i < n) atomicAdd(&lh[sid[i]], 1);
    __syncthreads();
    if (threadIdx.x < S_SYS) {
        int c = lh[threadIdx.x];
        if (c) atomicAdd(&hist[threadIdx.x * 16], c);
    }
}

// ---------------- scan: padded exclusive scan + immutable copy + total ------
__global__ void scan_k(int* __restrict__ ws) {
    if (threadIdx.x == 0 && blockIdx.x == 0) {
        int acc = 0;
        for (int t = 0; t < S_SYS; ++t) {
            ws[WS_CURSOR + t * 16] = acc;
            ws[WS_PSTART + t * 16] = acc;
            int c = ws[WS_HIST + t * 16];
            acc += ((c + SPB - 1) / SPB) * SPB;
        }
        ws[WS_NTOT] = acc;
    }
}

// ---------------- pad: sentinel-fill ONLY the bucket gaps (<2K entries) -----
__global__ void pad_k(const int* __restrict__ ws, unsigned* __restrict__ idx) {
    int t = blockIdx.x;                       // one block per system
    int base = ws[WS_PSTART + t * 16];
    int cnt  = ws[WS_HIST + t * 16];
    int pcnt = ((cnt + SPB - 1) / SPB) * SPB;
    for (int u = cnt + threadIdx.x; u < pcnt; u += blockDim.x)
        idx[base + u] = 0xFFFFFFFFu;
}

// ---------------- scatter: counting sort of sample indices ----------------
// entry = i | (s << 28); sentinel 0xFFFFFFFF cannot collide (i < 2^18).
__global__ __launch_bounds__(256) void scatter_k(const int* __restrict__ sid, int n,
                                                 int* __restrict__ cursor,
                                                 unsigned* __restrict__ idx) {
    __shared__ int wcnt[4][S_SYS];
    __shared__ int bbase[S_SYS];
    int i = blockIdx.x * 256 + threadIdx.x;
    int w = threadIdx.x >> 6;
    int lane = threadIdx.x & 63;
    int s = (i < n) ? sid[i] : -1;

    unsigned long long mym = 0;
    #pragma unroll 1
    for (int t = 0; t < S_SYS; ++t) {
        unsigned long long m = __ballot(s == t);
        if (lane == 0) wcnt[w][t] = (int)__popcll(m);
        if (s == t) mym = m;
    }
    int rank = (int)__popcll(mym & ((1ull << lane) - 1ull));
    __syncthreads();
    if (threadIdx.x < S_SYS) {
        int t = threadIdx.x, acc = 0;
        #pragma unroll
        for (int ww = 0; ww < 4; ++ww) { int c = wcnt[ww][t]; wcnt[ww][t] = acc; acc += c; }
        bbase[t] = atomicAdd(&cursor[t * 16], acc);
    }
    __syncthreads();
    if (i < n) {
        int pos = bbase[s] + wcnt[w][s] + rank;
        idx[pos] = (unsigned)i | ((unsigned)s << 28);
    }
}

// ---------------- main: W[s] in LDS, deep x prefetch ----------------
// Block = 256 threads = 4 waves; each wave owns NB=4 batches of 8 samples.
// q = lane&7 owns float4 chunks k*8+q -> each x load instr = 8 full 128B lines.
// All 32 x float4 loads per wave issue before compute (32 KB MLP/wave).
// Grid is a fixed upper bound (graph capture); live count read from ws[WS_NTOT].
__global__ __launch_bounds__(256) void main2_k(const float* __restrict__ x,
                                               const float* __restrict__ W,
                                               const float* __restrict__ b,
                                               const int* __restrict__ ws,
                                               const unsigned* __restrict__ idx,
                                               float* __restrict__ out) {
    __shared__ float4 Wl[C_CLS * D_DIM / 4];   // 640 float4 = 10 KB
    const int tid = threadIdx.x;
    const long bpos = (long)blockIdx.x * SPB;
    if (bpos >= (long)ws[WS_NTOT]) return;     // beyond padded total: idx undefined there
    const unsigned e0 = idx[bpos];             // first slot of a live block is always real
    const int s = (int)(e0 >> 28);

    const float4* __restrict__ Wg = (const float4*)W + (size_t)s * (C_CLS * D_DIM / 4);
    #pragma unroll
    for (int t = 0; t < 3; ++t) {
        int u = tid + t * 256;
        if (u < C_CLS * D_DIM / 4) Wl[u] = Wg[u];
    }
    __syncthreads();

    const int wv = tid >> 6, lane = tid & 63, r = lane >> 3, q = lane & 7;
    const long wpos = bpos + (long)wv * (8 * NB);

    unsigned e[NB]; int irow[NB];
    #pragma unroll
    for (int nb = 0; nb < NB; ++nb) {
        e[nb] = idx[wpos + nb * 8 + r];                       // broadcast across q-lanes
        irow[nb] = (e[nb] == 0xFFFFFFFFu) ? 0 : (int)(e[nb] & 0x0FFFFFFFu);
    }

    // ---- deep prefetch: all 32 x float4 loads in flight before compute ----
    const float4* __restrict__ xg = (const float4*)x;
    float4 xb[NB][8];
    #pragma unroll
    for (int nb = 0; nb < NB; ++nb) {
        const float4* xr = xg + (size_t)irow[nb] * (D_DIM / 4) + q;
        #pragma unroll
        for (int k = 0; k < 8; ++k) xb[nb][k] = xr[k * 8];
    }

    float acc[NB][C_CLS];
    #pragma unroll
    for (int nb = 0; nb < NB; ++nb)
        #pragma unroll
        for (int c = 0; c < C_CLS; ++c) acc[nb][c] = 0.f;

    #pragma unroll
    for (int k = 0; k < 8; ++k) {
        #pragma unroll
        for (int c = 0; c < C_CLS; ++c) {
            const float4 wvv = Wl[c * (D_DIM / 4) + k * 8 + q];
            #pragma unroll
            for (int nb = 0; nb < NB; ++nb) {
                acc[nb][c] = fmaf(xb[nb][k].x, wvv.x,
                             fmaf(xb[nb][k].y, wvv.y,
                              fmaf(xb[nb][k].z, wvv.z,
                               fmaf(xb[nb][k].w, wvv.w, acc[nb][c]))));
            }
        }
    }

    const float bq  = b[s * C_CLS + q];
    const float bq2 = (q < 2) ? b[s * C_CLS + 8 + q] : 0.f;

    #pragma unroll
    for (int nb = 0; nb < NB; ++nb) {
        float v0 = 0.f, v1 = 0.f;
        #pragma unroll
        for (int c = 0; c < C_CLS; ++c) {
            float v = acc[nb][c];
            v += __shfl_xor(v, 1);
            v += __shfl_xor(v, 2);
            v += __shfl_xor(v, 4);
            if (c == q)     v0 = v;   // compile-time index, runtime compare (no scratch)
            if (c == 8 + q) v1 = v;
        }
        if (e[nb] != 0xFFFFFFFFu) {
            float* op = out + (size_t)irow[nb] * C_CLS;
            op[q] = v0 + bq;
            if (q < 2) op[8 + q] = v1 + bq2;
        }
    }
}

// ---------------- fallback (workspace too small): thread-per-sample ----------------
__global__ __launch_bounds__(256) void fallback_k(const float* __restrict__ x,
                                                  const int* __restrict__ sid,
                                                  const float* __restrict__ W,
                                                  const float* __restrict__ b,
                                                  float* __restrict__ out, int n) {
    int i = blockIdx.x * 256 + threadIdx.x;
    if (i >= n) return;
    int s = sid[i];
    const float4* xr = (const float4*)(x) + (size_t)i * (D_DIM / 4);
    const float4* wr = (const float4*)(W) + (size_t)s * (C_CLS * D_DIM / 4);
    float acc[C_CLS];
    #pragma unroll
    for (int c = 0; c < C_CLS; ++c) acc[c] = 0.f;
    for (int k = 0; k < D_DIM / 4; ++k) {
        float4 xv = xr[k];
        #pragma unroll
        for (int c = 0; c < C_CLS; ++c) {
            float4 wv = wr[c * (D_DIM / 4) + k];
            acc[c] = fmaf(xv.x, wv.x, fmaf(xv.y, wv.y, fmaf(xv.z, wv.z, fmaf(xv.w, wv.w, acc[c]))));
        }
    }
    #pragma unroll
    for (int c = 0; c < C_CLS; ++c) out[(size_t)i * C_CLS + c] = acc[c] + b[s * C_CLS + c];
}

extern "C" void kernel_launch(void* const* d_in, const int* in_sizes, int n_in,
                              void* d_out, int out_size, void* d_ws, size_t ws_size,
                              hipStream_t stream) {
    const float* x = (const float*)d_in[0];
    const int* sid = (const int*)d_in[1];
    const float* W = (const float*)d_in[2];
    const float* b = (const float*)d_in[3];
    float* out = (float*)d_out;
    const int n = in_sizes[1];   // B

    const int nblk_main = (n + SPB - 1) / SPB + S_SYS;   // padded-bucket upper bound
    const size_t idx_entries = (size_t)nblk_main * SPB;
    const size_t ws_needed = WS_IDX_BYTES + idx_entries * sizeof(unsigned);

    if (ws_size < ws_needed) {
        fallback_k<<<(n + 255) / 256, 256, 0, stream>>>(x, sid, W, b, out, n);
        return;
    }

    int* ws = (int*)d_ws;
    unsigned* idx = (unsigned*)((char*)d_ws + WS_IDX_BYTES);

    const int blocks256 = (n + 255) / 256;
    init_k<<<1, 512, 0, stream>>>(ws);
    hist_k<<<blocks256, 256, 0, stream>>>(sid, n, ws + WS_HIST);
    scan_k<<<1, 64, 0, stream>>>(ws);
    pad_k<<<S_SYS, 128, 0, stream>>>(ws, idx);
    scatter_k<<<blocks256, 256, 0, stream>>>(sid, n, ws + WS_CURSOR, idx);
    main2_k<<<nblk_main, 256, 0, stream>>>(x, W, b, ws, idx, out);
}

// Round 5
// 131.491 us; speedup vs baseline: 1.1360x; 1.1360x over previous
//
#include <hip/hip_runtime.h>
#include <hip/hip_bf16.h>

// Problem constants (from reference): B=262144, D=256, S=16, C=10.
#define D_DIM 256
#define S_SYS 16
#define C_CLS 10
#define SPB   64    // bucket padding granule = wave size -> every wave single-system

// Workspace layout (ints):
//   [0   .. 255]  hist    (16 bins, 64B-strided: hist[t*16])
//   [256 .. 511]  cursor  (scatter-mutated)
//   [512 .. 767]  pstart  (immutable padded starts)
//   [768]         ntot    (padded total)
//   byte 4096+    idx     (sorted packed entries: i | s<<28; sentinel 0xFFFFFFFF)
#define WS_HIST   0
#define WS_CURSOR 256
#define WS_PSTART 512
#define WS_NTOT   768
#define WS_IDX_BYTES 4096

__global__ void init_k(int* __restrict__ ws) {
    if (threadIdx.x < 512) ws[threadIdx.x] = 0;
}

__global__ __launch_bounds__(256) void hist_k(const int* __restrict__ sid, int n,
                                              int* __restrict__ hist) {
    __shared__ int lh[S_SYS];
    if (threadIdx.x < S_SYS) lh[threadIdx.x] = 0;
    __syncthreads();
    int i = blockIdx.x * 256 + threadIdx.x;
    if (i < n) atomicAdd(&lh[sid[i]], 1);
    __syncthreads();
    if (threadIdx.x < S_SYS) {
        int c = lh[threadIdx.x];
        if (c) atomicAdd(&hist[threadIdx.x * 16], c);
    }
}

__global__ void scan_k(int* __restrict__ ws) {
    if (threadIdx.x == 0 && blockIdx.x == 0) {
        int acc = 0;
        for (int t = 0; t < S_SYS; ++t) {
            ws[WS_CURSOR + t * 16] = acc;
            ws[WS_PSTART + t * 16] = acc;
            int c = ws[WS_HIST + t * 16];
            acc += ((c + SPB - 1) / SPB) * SPB;
        }
        ws[WS_NTOT] = acc;
    }
}

// sentinel-fill ONLY bucket gaps (< 16*63 entries total)
__global__ void pad_k(const int* __restrict__ ws, unsigned* __restrict__ idx) {
    int t = blockIdx.x;
    int base = ws[WS_PSTART + t * 16];
    int cnt  = ws[WS_HIST + t * 16];
    int pcnt = ((cnt + SPB - 1) / SPB) * SPB;
    for (int u = cnt + threadIdx.x; u < pcnt; u += blockDim.x)
        idx[base + u] = 0xFFFFFFFFu;
}

__global__ __launch_bounds__(256) void scatter_k(const int* __restrict__ sid, int n,
                                                 int* __restrict__ cursor,
                                                 unsigned* __restrict__ idx) {
    __shared__ int wcnt[4][S_SYS];
    __shared__ int bbase[S_SYS];
    int i = blockIdx.x * 256 + threadIdx.x;
    int w = threadIdx.x >> 6;
    int lane = threadIdx.x & 63;
    int s = (i < n) ? sid[i] : -1;

    unsigned long long mym = 0;
    #pragma unroll 1
    for (int t = 0; t < S_SYS; ++t) {
        unsigned long long m = __ballot(s == t);
        if (lane == 0) wcnt[w][t] = (int)__popcll(m);
        if (s == t) mym = m;
    }
    int rank = (int)__popcll(mym & ((1ull << lane) - 1ull));
    __syncthreads();
    if (threadIdx.x < S_SYS) {
        int t = threadIdx.x, acc = 0;
        #pragma unroll
        for (int ww = 0; ww < 4; ++ww) { int c = wcnt[ww][t]; wcnt[ww][t] = acc; acc += c; }
        bbase[t] = atomicAdd(&cursor[t * 16], acc);
    }
    __syncthreads();
    if (i < n) {
        int pos = bbase[s] + wcnt[w][s] + rank;
        idx[pos] = (unsigned)i | ((unsigned)s << 28);
    }
}

// ---------------- main v3: thread-per-sample, W via wave-uniform s_loads ----
// Sorted order + SPB=64 padding -> each wave's 64 slots share one system s.
// readfirstlane(sid) -> W/b accesses are wave-uniform -> scalar loads (lgkmcnt),
// the vmcnt queue carries ONLY x. Each lane reads its row as 8 chunks of
// 8 consecutive float4 (= one 128B line, MSHR-merged), double-buffered so the
// next line is in flight during the current chunk's 320 FMAs. No LDS at all.
__global__ __launch_bounds__(256) void main3_k(const float* __restrict__ x,
                                               const float* __restrict__ W,
                                               const float* __restrict__ b,
                                               const int* __restrict__ ws,
                                               const unsigned* __restrict__ idx,
                                               float* __restrict__ out) {
    const int lane = threadIdx.x & 63;
    const long wid = ((long)blockIdx.x * blockDim.x + threadIdx.x) >> 6;
    const long slot0 = wid * 64;
    if (slot0 >= (long)ws[WS_NTOT]) return;          // fixed-grid gate (graph capture)

    const unsigned e = idx[slot0 + lane];
    // BUGFIX (round 4): shift the UNSIGNED value first (logical shift), then
    // readfirstlane. Previous code shifted readfirstlane's signed int result:
    // for s>=8 (bit 31 set) the arithmetic >>28 sign-extended -> negative s
    // -> OOB W reads for half the systems (absmax 1.76).
    // lane 0 of a live wave is always a real sample (pad sits at bucket tail).
    const int s = __builtin_amdgcn_readfirstlane((int)(e >> 28)) & (S_SYS - 1);
    const bool live = (e != 0xFFFFFFFFu);
    const int irow = live ? (int)(e & 0x0FFFFFFFu) : 0;

    const float* __restrict__ Wb = W + (size_t)s * (C_CLS * D_DIM);  // wave-uniform
    const float* __restrict__ bb = b + s * C_CLS;                    // wave-uniform
    const float4* __restrict__ xr = (const float4*)x + (size_t)irow * (D_DIM / 4);

    float acc[C_CLS];
    #pragma unroll
    for (int c = 0; c < C_CLS; ++c) acc[c] = bb[c];

    float4 xa[8], xq[8];
    #pragma unroll
    for (int j = 0; j < 8; ++j) xa[j] = xr[j];       // chunk 0 = line 0

    #pragma unroll 1
    for (int ch = 0; ch < 8; ch += 2) {
        // prefetch chunk ch+1 (next 128B line) into xq
        #pragma unroll
        for (int j = 0; j < 8; ++j) xq[j] = xr[(ch + 1) * 8 + j];
        // compute chunk ch from xa (W operands wave-uniform -> scalar)
        #pragma unroll
        for (int c = 0; c < C_CLS; ++c) {
            #pragma unroll
            for (int j = 0; j < 8; ++j) {
                const float* wp = Wb + c * D_DIM + ch * 32 + j * 4;
                acc[c] = fmaf(xa[j].x, wp[0],
                          fmaf(xa[j].y, wp[1],
                           fmaf(xa[j].z, wp[2],
                            fmaf(xa[j].w, wp[3], acc[c]))));
            }
        }
        // prefetch chunk ch+2 into xa
        if (ch + 2 < 8) {
            #pragma unroll
            for (int j = 0; j < 8; ++j) xa[j] = xr[(ch + 2) * 8 + j];
        }
        // compute chunk ch+1 from xq
        #pragma unroll
        for (int c = 0; c < C_CLS; ++c) {
            #pragma unroll
            for (int j = 0; j < 8; ++j) {
                const float* wp = Wb + c * D_DIM + (ch + 1) * 32 + j * 4;
                acc[c] = fmaf(xq[j].x, wp[0],
                          fmaf(xq[j].y, wp[1],
                           fmaf(xq[j].z, wp[2],
                            fmaf(xq[j].w, wp[3], acc[c]))));
            }
        }
    }

    if (live) {
        // 40B rows are 8B-aligned -> 5x float2 stores
        float2* op = (float2*)(out + (size_t)irow * C_CLS);
        #pragma unroll
        for (int t = 0; t < 5; ++t) op[t] = make_float2(acc[2 * t], acc[2 * t + 1]);
    }
}

// ---------------- fallback (workspace too small): thread-per-sample ----------------
__global__ __launch_bounds__(256) void fallback_k(const float* __restrict__ x,
                                                  const int* __restrict__ sid,
                                                  const float* __restrict__ W,
                                                  const float* __restrict__ b,
                                                  float* __restrict__ out, int n) {
    int i = blockIdx.x * 256 + threadIdx.x;
    if (i >= n) return;
    int s = sid[i];
    const float4* xr = (const float4*)(x) + (size_t)i * (D_DIM / 4);
    const float4* wr = (const float4*)(W) + (size_t)s * (C_CLS * D_DIM / 4);
    float acc[C_CLS];
    #pragma unroll
    for (int c = 0; c < C_CLS; ++c) acc[c] = 0.f;
    for (int k = 0; k < D_DIM / 4; ++k) {
        float4 xv = xr[k];
        #pragma unroll
        for (int c = 0; c < C_CLS; ++c) {
            float4 wv = wr[c * (D_DIM / 4) + k];
            acc[c] = fmaf(xv.x, wv.x, fmaf(xv.y, wv.y, fmaf(xv.z, wv.z, fmaf(xv.w, wv.w, acc[c]))));
        }
    }
    #pragma unroll
    for (int c = 0; c < C_CLS; ++c) out[(size_t)i * C_CLS + c] = acc[c] + b[s * C_CLS + c];
}

extern "C" void kernel_launch(void* const* d_in, const int* in_sizes, int n_in,
                              void* d_out, int out_size, void* d_ws, size_t ws_size,
                              hipStream_t stream) {
    const float* x = (const float*)d_in[0];
    const int* sid = (const int*)d_in[1];
    const float* W = (const float*)d_in[2];
    const float* b = (const float*)d_in[3];
    float* out = (float*)d_out;
    const int n = in_sizes[1];   // B

    const size_t idx_entries = (size_t)n + S_SYS * (SPB - 1);   // padded upper bound
    const size_t ws_needed = WS_IDX_BYTES + idx_entries * sizeof(unsigned);

    if (ws_size < ws_needed) {
        fallback_k<<<(n + 255) / 256, 256, 0, stream>>>(x, sid, W, b, out, n);
        return;
    }

    int* ws = (int*)d_ws;
    unsigned* idx = (unsigned*)((char*)d_ws + WS_IDX_BYTES);

    const int blocks256 = (n + 255) / 256;
    init_k<<<1, 512, 0, stream>>>(ws);
    hist_k<<<blocks256, 256, 0, stream>>>(sid, n, ws + WS_HIST);
    scan_k<<<1, 64, 0, stream>>>(ws);
    pad_k<<<S_SYS, 128, 0, stream>>>(ws, idx);
    scatter_k<<<blocks256, 256, 0, stream>>>(sid, n, ws + WS_CURSOR, idx);

    const int nblk_main = (int)((idx_entries + 255) / 256) + 1;  // fixed upper bound
    main3_k<<<nblk_main, 256, 0, stream>>>(x, W, b, ws, idx, out);
}